// Round 9
// baseline (1053.710 us; speedup 1.0000x reference)
//
#include <hip/hip_runtime.h>

#define NN 50000
#define NE 1600000
#define EP (NE + NN)          // edges + self loops = 1,650,000
#define D 128
#define H 4
#define NEG 0.2f
#define LN_EPS 1e-5f
#define NBUCK 49              // dst >> 10 buckets
#define BCAP 40960            // fixed bucket capacity (max ~35.5K used)
#define CHUNK 4096
#define NCHUNK 8              // src chunks (src >> 13); chunks 0..6 used
#define CSH 13
#define NSEG (NN * NCHUNK)    // 400000 (node, chunk) segments
#define NPW 8                 // nodes per wave in k_agg

typedef _Float16 f16;
typedef _Float16 half8 __attribute__((ext_vector_type(8)));
typedef _Float16 half4 __attribute__((ext_vector_type(4)));
typedef _Float16 half2v __attribute__((ext_vector_type(2)));
typedef float f32x4v __attribute__((ext_vector_type(4)));
typedef unsigned short u16;
typedef unsigned int u32;

static __device__ __forceinline__ float leakyf(float v) { return fmaxf(v, NEG * v); }

static __device__ __forceinline__ int fkey(float v) {
    int b = __float_as_int(v);
    return b >= 0 ? b : (b ^ 0x7fffffff);
}
static __device__ __forceinline__ float fdec(int k) {
    return __int_as_float(k >= 0 ? k : (k ^ 0x7fffffff));
}
#define NEG_INF_KEY 0x807fffff

// ---------- init: zero deg8/gmax/gcur + W->fp16 transposed + ws = W@B' ----------
__global__ void k_init(int* __restrict__ deg8, int* __restrict__ gmaxk,
                       int* __restrict__ gcur,
                       const float* __restrict__ w0, const float* __restrict__ w1,
                       const float* __restrict__ w2, f16* __restrict__ wt,
                       const float* __restrict__ as0, const float* __restrict__ ad0,
                       const float* __restrict__ as1, const float* __restrict__ ad1,
                       const float* __restrict__ as2, const float* __restrict__ ad2,
                       f16* __restrict__ ws16) {
    int t = blockIdx.x * blockDim.x + threadIdx.x;
    if (t < NSEG) deg8[t] = 0;
    if (t < 12) gmaxk[t] = NEG_INF_KEY;
    if (t < NBUCK) gcur[t] = 0;
    int u = t - 50176;
    if (u >= 0 && u < 3 * D * D) {
        int l = u / (D * D), rem = u % (D * D);
        int k = rem >> 7, c = rem & 127;
        const float* w = (l == 0) ? w0 : (l == 1) ? w1 : w2;
        wt[l * D * D + c * D + k] = (f16)w[rem];
    }
    int v = t - 99328;
    if (v >= 0 && v < 3 * 16 * D) {
        int l = v / (16 * D), rem = v % (16 * D);
        int c = rem >> 7, k = rem & 127;
        f16 out = (f16)0.f;
        if (c < 8) {
            int head = c >> 1;
            const float* w = (l == 0) ? w0 : (l == 1) ? w1 : w2;
            const float* av = (c & 1) ? ((l == 0) ? ad0 : (l == 1) ? ad1 : ad2)
                                      : ((l == 0) ? as0 : (l == 1) ? as1 : as2);
            float s = 0.f;
#pragma unroll
            for (int j = 0; j < 32; j++)
                s = fmaf(w[k * D + head * 32 + j], av[head * 32 + j], s);
            out = (f16)s;
        }
        ws16[l * 16 * D + c * D + k] = out;
    }
}

// phase 1: bin edges into fixed-capacity per-bucket streams (packed dst<<16|src)
__global__ __launch_bounds__(256) void k_bin(const int* __restrict__ ei,
                                             int* __restrict__ gcur,
                                             u32* __restrict__ binned) {
    __shared__ u32 pk[CHUNK];
    __shared__ int hist[NBUCK], base[NBUCK], lcur[NBUCK];
    int tid = threadIdx.x;
    int cbase = blockIdx.x * CHUNK;
    if (tid < NBUCK) hist[tid] = 0;
    __syncthreads();
#pragma unroll
    for (int j = 0; j < CHUNK / 256; j++) {
        int k = cbase + j * 256 + tid;
        u32 v = 0xFFFFFFFFu;
        if (k < EP) {
            int src, dst;
            if (k < NE) { src = ei[k]; dst = ei[NE + k]; }
            else        { src = k - NE; dst = src; }
            v = ((u32)dst << 16) | (u32)src;
            atomicAdd(&hist[dst >> 10], 1);
        }
        pk[j * 256 + tid] = v;
    }
    __syncthreads();
    if (tid < NBUCK) {
        base[tid] = atomicAdd(&gcur[tid], hist[tid]);
        lcur[tid] = 0;
    }
    __syncthreads();
#pragma unroll
    for (int j = 0; j < CHUNK / 256; j++) {
        u32 v = pk[j * 256 + tid];
        if (v != 0xFFFFFFFFu) {
            int b = v >> 26;  // (v>>16)>>10
            int pos = base[b] + atomicAdd(&lcur[b], 1);
            binned[(size_t)b * BCAP + pos] = v;
        }
    }
}

// per-(node,chunk) degree count via 32KB LDS histogram (4 blocks per bucket)
__global__ __launch_bounds__(1024) void k_cnt2(const int* __restrict__ gcur,
                                               const u32* __restrict__ binned,
                                               int* __restrict__ deg8) {
    __shared__ int hist[1024 * NCHUNK];   // 32 KB
    int b = blockIdx.x >> 2, sub = blockIdx.x & 3;
#pragma unroll
    for (int j = 0; j < NCHUNK; j++) hist[j * 1024 + threadIdx.x] = 0;
    __syncthreads();
    int cnt = gcur[b];
    const u32* bb = binned + (size_t)b * BCAP;
    for (int i = sub * 1024 + threadIdx.x; i < cnt; i += 4096) {
        u32 v = bb[i];
        int idx = (int)((v >> 16) & 1023) * NCHUNK + (int)((v & 0xffffu) >> CSH);
        atomicAdd(&hist[idx], 1);
    }
    __syncthreads();
    int nb0 = b << 10;
    for (int i = threadIdx.x; i < 1024 * NCHUNK; i += 1024) {
        int node = nb0 + (i >> 3);
        int hv = hist[i];
        if (node < NN && hv) atomicAdd(&deg8[node * NCHUNK + (i & 7)], hv);
    }
}

#define SCAN_B 1024
__global__ __launch_bounds__(1024) void k_scan1(const int* __restrict__ deg8,
                                                int* __restrict__ stmp, int* __restrict__ bsum) {
    __shared__ int sm[SCAN_B];
    int i = blockIdx.x * SCAN_B + threadIdx.x;
    sm[threadIdx.x] = (i < NSEG) ? ((deg8[i] + 1) & ~1) : 0;   // 2-aligned segment sizes
    __syncthreads();
    for (int off = 1; off < SCAN_B; off <<= 1) {
        int t = (threadIdx.x >= off) ? sm[threadIdx.x - off] : 0;
        __syncthreads();
        sm[threadIdx.x] += t;
        __syncthreads();
    }
    if (i < NSEG) stmp[i] = sm[threadIdx.x];
    if (threadIdx.x == SCAN_B - 1) bsum[blockIdx.x] = sm[SCAN_B - 1];
}

__global__ __launch_bounds__(1024) void k_scan2(int* __restrict__ bsum, int nb) {
    __shared__ int sm[1024];
    int v = (threadIdx.x < nb) ? bsum[threadIdx.x] : 0;
    sm[threadIdx.x] = v;
    __syncthreads();
    for (int off = 1; off < 1024; off <<= 1) {
        int t = (threadIdx.x >= off) ? sm[threadIdx.x - off] : 0;
        __syncthreads();
        sm[threadIdx.x] += t;
        __syncthreads();
    }
    if (threadIdx.x < nb) bsum[threadIdx.x] = sm[threadIdx.x];
}

__global__ __launch_bounds__(1024) void k_scan3(const int* __restrict__ stmp,
                                                const int* __restrict__ bsum, int* __restrict__ rowptr) {
    int i = blockIdx.x * SCAN_B + threadIdx.x;
    if (i >= NSEG) return;
    int add = (blockIdx.x > 0) ? bsum[blockIdx.x - 1] : 0;
    rowptr[i + 1] = stmp[i] + add;
    if (i == 0) rowptr[0] = 0;
}

// sentinel-pad each segment tail to the 2-aligned boundary; init cur = rowptr
__global__ void k_pad(const int* __restrict__ rowptr, const int* __restrict__ deg8,
                      int* __restrict__ cur, u16* __restrict__ csr) {
    int i = blockIdx.x * blockDim.x + threadIdx.x;
    if (i >= NSEG) return;
    int rp = rowptr[i];
    cur[i] = rp;
    int d = deg8[i];
    int ad = (d + 1) & ~1;
    for (int j = d; j < ad; ++j) csr[rp + j] = 0xFFFFu;
}

// phase 2: per-bucket scatter into (dst, chunk) segments (4 blocks per bucket)
__global__ __launch_bounds__(1024) void k_scatter(const int* __restrict__ gcur,
                                                  int* __restrict__ cur,
                                                  const u32* __restrict__ binned,
                                                  u16* __restrict__ csr) {
    int b = blockIdx.x >> 2, sub = blockIdx.x & 3;
    int cnt = gcur[b];
    const u32* bb = binned + (size_t)b * BCAP;
    for (int i = sub * 1024 + threadIdx.x; i < cnt; i += 4096) {
        u32 v = bb[i];
        int dst = v >> 16;
        int src = v & 0xffffu;
        int pos = atomicAdd(&cur[dst * NCHUNK + (src >> CSH)], 1);
        csr[pos] = (u16)src;
    }
}

// ------------------------- input projection (fp16 residual carry) ---------------
__global__ void k_in(const float* __restrict__ x, const float* __restrict__ w,
                     const float* __restrict__ b, f16* __restrict__ h16) {
    int t = blockIdx.x * blockDim.x + threadIdx.x;
    if (t >= NN * D) return;
    int n = t >> 7, d = t & 127;
    const float* xr = x + n * 5;
    float acc = b[d];
#pragma unroll
    for (int k = 0; k < 5; k++) acc = fmaf(xr[k], w[k * D + d], acc);
    h16[t] = (f16)acc;
}

// --- MFMA GEMM: xh = h16 @ W16; als/ald via extra MFMA tile (ws); global max ---
__global__ __launch_bounds__(256) void k_gemm(const f16* __restrict__ h16,
                                              const f16* __restrict__ wt,
                                              const f16* __restrict__ ws16,
                                              f16* __restrict__ xh,
                                              float* __restrict__ als,
                                              float* __restrict__ ald,
                                              int* __restrict__ gmaxk) {
    __shared__ int sgk[4];
    if (threadIdx.x < 4) sgk[threadIdx.x] = NEG_INF_KEY;
    int wid = threadIdx.x >> 6;
    int lane = threadIdx.x & 63;
    int wbase = blockIdx.x * 128 + wid * 32;
    int r = lane & 15;
    int g = lane >> 4;

    int arow0 = wbase + r;      if (arow0 >= NN) arow0 = NN - 1;
    int arow1 = wbase + 16 + r; if (arow1 >= NN) arow1 = NN - 1;
    const f16* a0p = h16 + (size_t)arow0 * D + g * 8;
    const f16* a1p = h16 + (size_t)arow1 * D + g * 8;

    f32x4v acc0[8], acc1[8], al0, al1;
#pragma unroll
    for (int nt = 0; nt < 8; nt++) {
        acc0[nt] = (f32x4v){0.f, 0.f, 0.f, 0.f};
        acc1[nt] = (f32x4v){0.f, 0.f, 0.f, 0.f};
    }
    al0 = (f32x4v){0.f, 0.f, 0.f, 0.f};
    al1 = (f32x4v){0.f, 0.f, 0.f, 0.f};

#pragma unroll
    for (int ks = 0; ks < 4; ks++) {
        half8 a0 = *(const half8*)(a0p + ks * 32);
        half8 a1 = *(const half8*)(a1p + ks * 32);
        half8 bal = *(const half8*)(ws16 + (size_t)r * D + ks * 32 + g * 8);
        al0 = __builtin_amdgcn_mfma_f32_16x16x32_f16(a0, bal, al0, 0, 0, 0);
        al1 = __builtin_amdgcn_mfma_f32_16x16x32_f16(a1, bal, al1, 0, 0, 0);
#pragma unroll
        for (int nt = 0; nt < 8; nt++) {
            half8 b = *(const half8*)(wt + (size_t)(nt * 16 + r) * D + ks * 32 + g * 8);
            acc0[nt] = __builtin_amdgcn_mfma_f32_16x16x32_f16(a0, b, acc0[nt], 0, 0, 0);
            acc1[nt] = __builtin_amdgcn_mfma_f32_16x16x32_f16(a1, b, acc1[nt], 0, 0, 0);
        }
    }

#pragma unroll
    for (int rg = 0; rg < 4; rg++) {
        int n0 = wbase + g * 4 + rg;
        if (n0 < NN) {
#pragma unroll
            for (int nt = 0; nt < 8; nt++)
                xh[(size_t)n0 * D + nt * 16 + r] = (f16)acc0[nt][rg];
        }
        int n1 = wbase + 16 + g * 4 + rg;
        if (n1 < NN) {
#pragma unroll
            for (int nt = 0; nt < 8; nt++)
                xh[(size_t)n1 * D + nt * 16 + r] = (f16)acc1[nt][rg];
        }
    }

    float m = -1e30f;
#pragma unroll
    for (int rg = 0; rg < 4; rg++) {
        int n0 = wbase + g * 4 + rg;
        int n1 = wbase + 16 + g * 4 + rg;
        float v0 = al0[rg], v1 = al1[rg];
        if (r < 8) {
            int hh = r >> 1;
            if (r & 1) {
                if (n0 < NN) ald[n0 * H + hh] = v0;
                if (n1 < NN) ald[n1 * H + hh] = v1;
            } else {
                if (n0 < NN) als[n0 * H + hh] = v0;
                if (n1 < NN) als[n1 * H + hh] = v1;
                m = fmaxf(m, fmaxf(v0, v1));
            }
        }
    }
    m = fmaxf(m, __shfl_xor(m, 16));
    m = fmaxf(m, __shfl_xor(m, 32));
    __syncthreads();
    if (lane < 8 && !(r & 1)) atomicMax(&sgk[r >> 1], fkey(m));
    __syncthreads();
    if (threadIdx.x < 4) atomicMax(&gmaxk[threadIdx.x], sgk[threadIdx.x]);
}

// ---- chunked aggregation: 8 nodes/wave, src-chunk passes, + bias/LN/relu/residual
// lane = slot(1b) | q(5b): slot = edge slot 0..1, q -> dims q*4..q*4+3, head = q>>3
__global__ __launch_bounds__(256, 6) void k_agg(const f16* __restrict__ xh,
                                                const float* __restrict__ als,
                                                const float* __restrict__ ald,
                                                const int* __restrict__ gmaxk,
                                                const int* __restrict__ rp,
                                                const u16* __restrict__ csr,
                                                const float* __restrict__ cb,
                                                const float* __restrict__ gamma,
                                                const float* __restrict__ beta,
                                                f16* __restrict__ h16,
                                                float* __restrict__ hout, int do_relu) {
    int wid = threadIdx.x >> 6;
    int lane = threadIdx.x & 63;
    int nbase = (blockIdx.x * 4 + wid) * NPW;
    int slot = lane >> 5;
    int q = lane & 31;
    int head = q >> 3;
    int sh = slot << 4;

    float acc[NPW][4];
    float den[NPW];
#pragma unroll
    for (int n = 0; n < NPW; n++) {
        den[n] = 0.f;
        acc[n][0] = acc[n][1] = acc[n][2] = acc[n][3] = 0.f;
    }

    float gm = fdec(gmaxk[head]);

    for (int p = 0; p < 7; ++p) {             // src chunks 0..6 (49999>>13 == 6)
#pragma unroll
        for (int n = 0; n < NPW; n++) {
            int node = nbase + n;
            if (node >= NN) continue;
            float adH = ald[node * H + head];
            float mH = leakyf(gm + adH);      // upper bound on segment max
            int seg = node * NCHUNK + p;
            int s0 = rp[seg], s1 = rp[seg + 1];
            for (int e = s0; e < s1; e += 2) {
                u32 cw = *(const u32*)(csr + e);   // 2 edge srcs (broadcast)
                unsigned s = (cw >> sh) & 0xffffu;
                bool valid = s != 0xffffu;
                unsigned sc = valid ? s : 0u;
                float al = als[sc * H + head];
                float ev = valid ? __expf(leakyf(al + adH) - mH) : 0.f;
                den[n] += ev;
                half4 pv = *(const half4*)(xh + (size_t)sc * D + q * 4);
                acc[n][0] = fmaf(ev, (float)pv[0], acc[n][0]);
                acc[n][1] = fmaf(ev, (float)pv[1], acc[n][1]);
                acc[n][2] = fmaf(ev, (float)pv[2], acc[n][2]);
                acc[n][3] = fmaf(ev, (float)pv[3], acc[n][3]);
            }
        }
    }

    float4 cb4 = ((const float4*)cb)[q];
    float4 g4 = ((const float4*)gamma)[q];
    float4 b4 = ((const float4*)beta)[q];

#pragma unroll
    for (int n = 0; n < NPW; n++) {
        int node = nbase + n;
        if (node >= NN) continue;
        // reduce edge slots (lanes l, l^32 share the same dims)
        float d = den[n] + __shfl_xor(den[n], 32);
        float o0 = acc[n][0] + __shfl_xor(acc[n][0], 32);
        float o1 = acc[n][1] + __shfl_xor(acc[n][1], 32);
        float o2 = acc[n][2] + __shfl_xor(acc[n][2], 32);
        float o3 = acc[n][3] + __shfl_xor(acc[n][3], 32);
        float inv_den = 1.f / (d + 1e-16f);
        o0 = fmaf(o0, inv_den, cb4.x);
        o1 = fmaf(o1, inv_den, cb4.y);
        o2 = fmaf(o2, inv_den, cb4.z);
        o3 = fmaf(o3, inv_den, cb4.w);

        float s = o0 + o1 + o2 + o3;
#pragma unroll
        for (int off = 1; off < 32; off <<= 1) s += __shfl_xor(s, off);
        float mean = s * (1.f / 128.f);
        float c0 = o0 - mean, c1 = o1 - mean, c2 = o2 - mean, c3 = o3 - mean;
        float v = c0 * c0 + c1 * c1 + c2 * c2 + c3 * c3;
#pragma unroll
        for (int off = 1; off < 32; off <<= 1) v += __shfl_xor(v, off);
        float inv = rsqrtf(v * (1.f / 128.f) + LN_EPS);

        float r0 = c0 * inv * g4.x + b4.x;
        float r1 = c1 * inv * g4.y + b4.y;
        float r2 = c2 * inv * g4.z + b4.z;
        float r3 = c3 * inv * g4.w + b4.w;
        if (do_relu) {
            r0 = fmaxf(r0, 0.f); r1 = fmaxf(r1, 0.f);
            r2 = fmaxf(r2, 0.f); r3 = fmaxf(r3, 0.f);
        }
        if (slot == 0) {
            half4 hv = *(const half4*)&h16[(size_t)node * D + q * 4];
            float n0 = (float)hv[0] + r0;
            float n1 = (float)hv[1] + r1;
            float n2 = (float)hv[2] + r2;
            float n3 = (float)hv[3] + r3;
            if (do_relu) {
                half4 h2; h2[0] = (f16)n0; h2[1] = (f16)n1; h2[2] = (f16)n2; h2[3] = (f16)n3;
                *(half4*)&h16[(size_t)node * D + q * 4] = h2;
            } else {
                *(float4*)&hout[(size_t)node * D + q * 4] = (float4){n0, n1, n2, n3};
            }
        }
    }
}

// ------------------------- launch -------------------------
extern "C" void kernel_launch(void* const* d_in, const int* in_sizes, int n_in,
                              void* d_out, int out_size, void* d_ws, size_t ws_size,
                              hipStream_t stream) {
    const float* x    = (const float*)d_in[0];
    const float* w_in = (const float*)d_in[1];
    const float* b_in = (const float*)d_in[2];
    const int*   ei   = (const int*)d_in[21];
    float* hout = (float*)d_out;

    char* w = (char*)d_ws;
    int* deg8   = (int*)w;  w += (size_t)NSEG * 4;
    int* cur    = (int*)w;  w += (size_t)NSEG * 4;
    int* stmp   = (int*)w;  w += (size_t)NSEG * 4;
    int* bsum   = (int*)w;  w += 4096;
    int* rowptr = (int*)w;  w += (size_t)(NSEG + 8) * 4;
    int* gmaxk  = (int*)w;  w += 64;
    int* gcur   = (int*)w;  w += 256;
    u16* csr    = (u16*)w;  w += (size_t)(EP + NSEG + 64) * 2;
    f16* h16    = (f16*)w;  w += (size_t)NN * D * 2;
    f16* xh     = (f16*)w;  w += (size_t)NN * D * 2;
    f16* wt     = (f16*)w;  w += (size_t)3 * D * D * 2;
    f16* ws16   = (f16*)w;  w += (size_t)3 * 16 * D * 2;
    float* als  = (float*)w; w += (size_t)NN * H * 4;
    float* ald  = (float*)w; w += (size_t)NN * H * 4;
    u32* binned = (u32*)h16;  // h16 first written by k_in AFTER scatter; 8.03MB < 12.8MB

    k_init<<<1563, 256, 0, stream>>>(deg8, gmaxk, gcur,
                                     (const float*)d_in[3], (const float*)d_in[9],
                                     (const float*)d_in[15], wt,
                                     (const float*)d_in[4], (const float*)d_in[5],
                                     (const float*)d_in[10], (const float*)d_in[11],
                                     (const float*)d_in[16], (const float*)d_in[17],
                                     ws16);
    k_bin<<<(EP + CHUNK - 1) / CHUNK, 256, 0, stream>>>(ei, gcur, binned);
    k_cnt2<<<NBUCK * 4, 1024, 0, stream>>>(gcur, binned, deg8);
    int nbScan = (NSEG + SCAN_B - 1) / SCAN_B;  // 391
    k_scan1<<<nbScan, SCAN_B, 0, stream>>>(deg8, stmp, bsum);
    k_scan2<<<1, 1024, 0, stream>>>(bsum, nbScan);
    k_scan3<<<nbScan, SCAN_B, 0, stream>>>(stmp, bsum, rowptr);
    k_pad<<<(NSEG + 255) / 256, 256, 0, stream>>>(rowptr, deg8, cur, csr);
    k_scatter<<<NBUCK * 4, 1024, 0, stream>>>(gcur, cur, binned, csr);

    k_in<<<(NN * D) / 256, 256, 0, stream>>>(x, w_in, b_in, h16);

    int aggBlocks = (NN + 4 * NPW - 1) / (4 * NPW);   // 1563
    for (int L = 0; L < 3; ++L) {
        const float* cb   = (const float*)d_in[6 + 6 * L];
        const float* g    = (const float*)d_in[7 + 6 * L];
        const float* lb   = (const float*)d_in[8 + 6 * L];
        k_gemm<<<(NN + 127) / 128, 256, 0, stream>>>(h16, wt + (size_t)L * D * D,
                                                     ws16 + (size_t)L * 16 * D,
                                                     xh, als, ald, gmaxk + 4 * L);
        k_agg<<<aggBlocks, 256, 0, stream>>>(xh, als, ald, gmaxk + 4 * L, rowptr, csr,
                                             cb, g, lb, h16, hout, L < 2 ? 1 : 0);
    }
}